// Round 1
// baseline (413.401 us; speedup 1.0000x reference)
//
#include <hip/hip_runtime.h>

#define BB 16
#define NNODE 207
#define TTS 12
#define NE 1863
#define NH 8
#define FD 768
#define HFD 6144
#define MM 3312   // BB*NNODE
#define MP 3328   // padded to 26*128

typedef short bf16x8 __attribute__((ext_vector_type(8)));
typedef float f32x4 __attribute__((ext_vector_type(4)));

__device__ __forceinline__ unsigned short f2b(float f) {
    unsigned int u = __float_as_uint(f);
    u = (u + 0x7FFFu + ((u >> 16) & 1u)) >> 16;
    return (unsigned short)u;
}
__device__ __forceinline__ float b2f(unsigned short b) {
    return __uint_as_float(((unsigned int)b) << 16);
}

// ---------------- W transpose: W[k][n] (f32) -> Wt[n][k] (bf16) ----------------
__global__ __launch_bounds__(256) void transpose_w(const float* __restrict__ W,
                                                   unsigned short* __restrict__ Wt) {
    __shared__ float tile[64][65];
    const int k0 = blockIdx.x * 64;  // 768/64 = 12
    const int n0 = blockIdx.y * 64;  // 6144/64 = 96
    const int c = threadIdx.x & 63, r0 = threadIdx.x >> 6;
#pragma unroll
    for (int i = 0; i < 16; i++) {
        int r = r0 + i * 4;
        tile[r][c] = W[(size_t)(k0 + r) * HFD + n0 + c];
    }
    __syncthreads();
#pragma unroll
    for (int i = 0; i < 16; i++) {
        int r = r0 + i * 4;
        Wt[(size_t)(n0 + r) * FD + k0 + c] = f2b(tile[c][r]);
    }
}

// ---------------- 1x1 convs -> h0 (f32) + hbf (bf16, padded rows zeroed) -------
__global__ __launch_bounds__(256) void prep_h(const float* __restrict__ x,
                                              const float* __restrict__ Ws, const float* __restrict__ bs,
                                              const float* __restrict__ Wc, const float* __restrict__ bc,
                                              float* __restrict__ h0, unsigned short* __restrict__ hbf) {
    const int bn = blockIdx.x;
    const int t = threadIdx.x;
    if (bn >= MM) {
#pragma unroll
        for (int c = 0; c < 3; c++) hbf[(size_t)bn * FD + c * 256 + t] = 0;
        return;
    }
    const int b = bn / NNODE, n = bn % NNODE;
#pragma unroll
    for (int c = 0; c < 3; c++) {
        int idx = c * 256 + t;          // 0..767
        int e = idx / TTS, tt = idx % TTS;
        float x0 = x[((size_t)(b * 2 + 0) * NNODE + n) * TTS + tt];
        float x1 = x[((size_t)(b * 2 + 1) * NNODE + n) * TTS + tt];
        float s1 = Ws[e * 2] * x0 + Ws[e * 2 + 1] * x1 + bs[e];
        float s2 = Wc[e * 2] * x0 + Wc[e * 2 + 1] * x1 + bc[e];
        s2 = s2 > 0.f ? s2 : 0.01f * s2;
        float v = s1 + s2;
        h0[(size_t)bn * FD + idx] = v;
        hbf[(size_t)bn * FD + idx] = f2b(v);
    }
}

// ---------------- deterministic CSR by dst (single block) ----------------------
__global__ __launch_bounds__(256) void build_csr(const int* __restrict__ dst,
                                                 int* __restrict__ ptr, int* __restrict__ idx) {
    __shared__ int dl[NE];
    __shared__ int deg[NNODE];
    __shared__ int ps[NNODE + 1];
    const int t = threadIdx.x;
    for (int i = t; i < NE; i += 256) dl[i] = dst[i];
    __syncthreads();
    if (t < NNODE) {
        int c = 0;
        for (int i = 0; i < NE; i++) c += (dl[i] == t);
        deg[t] = c;
    }
    __syncthreads();
    if (t == 0) {
        ps[0] = 0;
        for (int n = 0; n < NNODE; n++) ps[n + 1] = ps[n] + deg[n];
    }
    __syncthreads();
    if (t < NNODE) {
        int p = ps[t];
        for (int i = 0; i < NE; i++)
            if (dl[i] == t) idx[p++] = i;
    }
    if (t <= NNODE) ptr[t] = ps[t];
}

// ---------------- MFMA GEMM: C[MM][HFD] = A[MP][FD] @ Bt[HFD][FD]^T (bf16) -----
#define LDT 40  // padded LDS row (bf16 elems) = 80B -> (5*row+slot)%8 bank spread
__global__ __launch_bounds__(256) void gemm_bf16(const unsigned short* __restrict__ A,
                                                 const unsigned short* __restrict__ Bt,
                                                 unsigned short* __restrict__ C) {
    __shared__ __align__(16) unsigned short Alds[128 * LDT];
    __shared__ __align__(16) unsigned short Blds[128 * LDT];
    const int t = threadIdx.x;
    const int lane = t & 63;
    const int wv = t >> 6;
    const int wr = (wv >> 1) * 64, wc = (wv & 1) * 64;
    const int mt = blockIdx.y * 128, nt = blockIdx.x * 128;
    const int lm = lane & 15;
    const int kb = (lane >> 4) * 8;
    const int srow = t >> 2;            // 0..63
    const int sseg = (t & 3) * 8;       // 0,8,16,24

    f32x4 acc[4][4] = {};
    for (int ks = 0; ks < FD; ks += 32) {
        uint4 va0 = *(const uint4*)(A + (size_t)(mt + srow) * FD + ks + sseg);
        uint4 va1 = *(const uint4*)(A + (size_t)(mt + srow + 64) * FD + ks + sseg);
        uint4 vb0 = *(const uint4*)(Bt + (size_t)(nt + srow) * FD + ks + sseg);
        uint4 vb1 = *(const uint4*)(Bt + (size_t)(nt + srow + 64) * FD + ks + sseg);
        *(uint4*)(Alds + srow * LDT + sseg) = va0;
        *(uint4*)(Alds + (srow + 64) * LDT + sseg) = va1;
        *(uint4*)(Blds + srow * LDT + sseg) = vb0;
        *(uint4*)(Blds + (srow + 64) * LDT + sseg) = vb1;
        __syncthreads();
        bf16x8 af[4], bfv[4];
#pragma unroll
        for (int i = 0; i < 4; i++) af[i] = *(const bf16x8*)(Alds + (wr + i * 16 + lm) * LDT + kb);
#pragma unroll
        for (int j = 0; j < 4; j++) bfv[j] = *(const bf16x8*)(Blds + (wc + j * 16 + lm) * LDT + kb);
#pragma unroll
        for (int i = 0; i < 4; i++)
#pragma unroll
            for (int j = 0; j < 4; j++)
                acc[i][j] = __builtin_amdgcn_mfma_f32_16x16x32_bf16(af[i], bfv[j], acc[i][j], 0, 0, 0);
        __syncthreads();
    }
    const int rbase = (lane >> 4) * 4;
#pragma unroll
    for (int i = 0; i < 4; i++) {
#pragma unroll
        for (int r = 0; r < 4; r++) {
            int grow = mt + wr + i * 16 + rbase + r;
            if (grow < MM) {
#pragma unroll
                for (int j = 0; j < 4; j++) {
                    int gcol = nt + wc + j * 16 + lm;
                    C[(size_t)grow * HFD + gcol] = f2b(acc[i][j][r]);
                }
            }
        }
    }
}

// ---------------- el/er: one wave per (bn, head) -------------------------------
__global__ __launch_bounds__(256) void eler(const unsigned short* __restrict__ feat,
                                            const float* __restrict__ al, const float* __restrict__ ar,
                                            float* __restrict__ el, float* __restrict__ er) {
    const int p = blockIdx.x * 4 + (threadIdx.x >> 6);  // 26496 pairs
    const int lane = threadIdx.x & 63;
    const int bn = p >> 3, hh = p & 7;
    const size_t base = (size_t)bn * HFD + hh * FD;
    float sl = 0.f, sr = 0.f;
#pragma unroll
    for (int j = 0; j < 12; j++) {
        int f = lane + j * 64;
        float fv = b2f(feat[base + f]);
        sl += fv * al[hh * FD + f];
        sr += fv * ar[hh * FD + f];
    }
#pragma unroll
    for (int off = 32; off > 0; off >>= 1) {
        sl += __shfl_down(sl, off);
        sr += __shfl_down(sr, off);
    }
    if (lane == 0) {
        el[bn * NH + hh] = sl;
        er[bn * NH + hh] = sr;
    }
}

// ---------------- edge softmax: one thread per (b,n,h) -------------------------
__global__ __launch_bounds__(256) void edge_softmax(const float* __restrict__ el, const float* __restrict__ er,
                                                    const int* __restrict__ cptr, const int* __restrict__ cidx,
                                                    const int* __restrict__ src, float* __restrict__ alp) {
    const int t = blockIdx.x * 256 + threadIdx.x;
    if (t >= BB * NNODE * NH) return;
    const int hh = t & 7;
    const int n = (t >> 3) % NNODE;
    const int b = t / (NNODE * NH);
    const float erv = er[(b * NNODE + n) * NH + hh];
    const int p0 = cptr[n], p1 = cptr[n + 1];
    float m = -1e30f;
    for (int j = p0; j < p1; j++) {
        int e = cidx[j];
        float s = el[(b * NNODE + src[e]) * NH + hh] + erv;
        s = s > 0.f ? s : 0.2f * s;
        m = fmaxf(m, s);
    }
    float den = 0.f;
    for (int j = p0; j < p1; j++) {
        int e = cidx[j];
        float s = el[(b * NNODE + src[e]) * NH + hh] + erv;
        s = s > 0.f ? s : 0.2f * s;
        float ex = expf(s - m);
        den += ex;
        alp[((size_t)b * NE + e) * NH + hh] = ex;
    }
    const float inv = 1.f / den;
    for (int j = p0; j < p1; j++) {
        int e = cidx[j];
        alp[((size_t)b * NE + e) * NH + hh] *= inv;
    }
}

// ---------------- message passing + elu + head-mean ----------------------------
template <int LAST>
__global__ __launch_bounds__(256) void msg_agg(const unsigned short* __restrict__ feat,
                                               const float* __restrict__ alp,
                                               const int* __restrict__ cptr, const int* __restrict__ cidx,
                                               const int* __restrict__ src, const float* __restrict__ bias,
                                               unsigned short* __restrict__ hbf_out,
                                               const float* __restrict__ h0, float* __restrict__ out) {
    __shared__ float rstl[HFD];         // 24 KB
    __shared__ int src_l[32];
    __shared__ float alph[32][NH];
    const int bn = blockIdx.x;
    const int b = bn / NNODE, n = bn % NNODE;
    const int t = threadIdx.x;
    const int h0i = t / 96, h1i = (256 + t) / 96, h2i = (512 + t) / 96;
    float acc[3][8] = {};
    const int p0 = cptr[n], p1 = cptr[n + 1];
    for (int base = p0; base < p1; base += 32) {
        const int cnt = min(32, p1 - base);
        if (t < cnt) src_l[t] = src[cidx[base + t]];
        {
            int j = t >> 3, hh = t & 7;
            if (j < cnt) alph[j][hh] = alp[((size_t)b * NE + cidx[base + j]) * NH + hh];
        }
        __syncthreads();
        for (int j2 = 0; j2 < cnt; j2++) {
            const size_t srow = (size_t)(b * NNODE + src_l[j2]) * HFD;
            const float a0 = alph[j2][h0i], a1 = alph[j2][h1i], a2 = alph[j2][h2i];
            uint4 pk;
            unsigned int w;
            pk = *(const uint4*)(feat + srow + (size_t)(0 * 256 + t) * 8);
            w = pk.x; acc[0][0] += a0 * b2f((unsigned short)w); acc[0][1] += a0 * b2f((unsigned short)(w >> 16));
            w = pk.y; acc[0][2] += a0 * b2f((unsigned short)w); acc[0][3] += a0 * b2f((unsigned short)(w >> 16));
            w = pk.z; acc[0][4] += a0 * b2f((unsigned short)w); acc[0][5] += a0 * b2f((unsigned short)(w >> 16));
            w = pk.w; acc[0][6] += a0 * b2f((unsigned short)w); acc[0][7] += a0 * b2f((unsigned short)(w >> 16));
            pk = *(const uint4*)(feat + srow + (size_t)(1 * 256 + t) * 8);
            w = pk.x; acc[1][0] += a1 * b2f((unsigned short)w); acc[1][1] += a1 * b2f((unsigned short)(w >> 16));
            w = pk.y; acc[1][2] += a1 * b2f((unsigned short)w); acc[1][3] += a1 * b2f((unsigned short)(w >> 16));
            w = pk.z; acc[1][4] += a1 * b2f((unsigned short)w); acc[1][5] += a1 * b2f((unsigned short)(w >> 16));
            w = pk.w; acc[1][6] += a1 * b2f((unsigned short)w); acc[1][7] += a1 * b2f((unsigned short)(w >> 16));
            pk = *(const uint4*)(feat + srow + (size_t)(2 * 256 + t) * 8);
            w = pk.x; acc[2][0] += a2 * b2f((unsigned short)w); acc[2][1] += a2 * b2f((unsigned short)(w >> 16));
            w = pk.y; acc[2][2] += a2 * b2f((unsigned short)w); acc[2][3] += a2 * b2f((unsigned short)(w >> 16));
            w = pk.z; acc[2][4] += a2 * b2f((unsigned short)w); acc[2][5] += a2 * b2f((unsigned short)(w >> 16));
            w = pk.w; acc[2][6] += a2 * b2f((unsigned short)w); acc[2][7] += a2 * b2f((unsigned short)(w >> 16));
        }
        __syncthreads();
    }
#pragma unroll
    for (int c = 0; c < 3; c++) {
        int v = c * 256 + t;
#pragma unroll
        for (int u = 0; u < 8; u++) rstl[v * 8 + u] = acc[c][u];
    }
    __syncthreads();
#pragma unroll
    for (int q = 0; q < 3; q++) {
        int f = q * 256 + t;
        float val = 0.f;
#pragma unroll
        for (int hh = 0; hh < 8; hh++) {
            float r = rstl[hh * FD + f] + bias[hh * FD + f];
            val += (r > 0.f) ? r : (expf(r) - 1.f);
        }
        val *= 0.125f;
        if (LAST) {
            int e_ = f / TTS, tt_ = f % TTS;
            out[((size_t)(b * 64 + e_) * NNODE + n) * TTS + tt_] = h0[(size_t)bn * FD + f] + val;
        } else {
            hbf_out[(size_t)bn * FD + f] = f2b(val);
        }
    }
}

extern "C" void kernel_launch(void* const* d_in, const int* in_sizes, int n_in,
                              void* d_out, int out_size, void* d_ws, size_t ws_size,
                              hipStream_t stream) {
    const float* x = (const float*)d_in[0];
    const int* src = (const int*)d_in[1];
    const int* dst = (const int*)d_in[2];
    const float* Ws = (const float*)d_in[3];
    const float* bs = (const float*)d_in[4];
    const float* Wc = (const float*)d_in[5];
    const float* bc = (const float*)d_in[6];
    const float* W1 = (const float*)d_in[7];
    const float* al1 = (const float*)d_in[8];
    const float* ar1 = (const float*)d_in[9];
    const float* b1 = (const float*)d_in[10];
    const float* W2 = (const float*)d_in[11];
    const float* al2 = (const float*)d_in[12];
    const float* ar2 = (const float*)d_in[13];
    const float* b2 = (const float*)d_in[14];
    float* out = (float*)d_out;

    char* w = (char*)d_ws;
    size_t off = 0;
    auto alloc = [&](size_t bytes) -> void* {
        void* p = w + off;
        off = (off + bytes + 255) & ~(size_t)255;
        return p;
    };
    float* h0 = (float*)alloc((size_t)MM * FD * 4);
    unsigned short* hbf = (unsigned short*)alloc((size_t)MP * FD * 2);
    unsigned short* Wt = (unsigned short*)alloc((size_t)HFD * FD * 2);
    unsigned short* feat = (unsigned short*)alloc((size_t)MM * HFD * 2);
    float* el = (float*)alloc((size_t)MM * NH * 4);
    float* er = (float*)alloc((size_t)MM * NH * 4);
    float* alp = (float*)alloc((size_t)BB * NE * NH * 4);
    int* cptr = (int*)alloc((NNODE + 1) * 4);
    int* cidx = (int*)alloc(NE * 4);

    // prep
    transpose_w<<<dim3(12, 96), 256, 0, stream>>>(W1, Wt);
    prep_h<<<MP, 256, 0, stream>>>(x, Ws, bs, Wc, bc, h0, hbf);
    build_csr<<<1, 256, 0, stream>>>(dst, cptr, cidx);

    // layer 1
    gemm_bf16<<<dim3(48, 26), 256, 0, stream>>>(hbf, Wt, feat);
    transpose_w<<<dim3(12, 96), 256, 0, stream>>>(W2, Wt);  // Wt free after gemm1
    eler<<<6624, 256, 0, stream>>>(feat, al1, ar1, el, er);
    edge_softmax<<<104, 256, 0, stream>>>(el, er, cptr, cidx, src, alp);
    msg_agg<0><<<MM, 256, 0, stream>>>(feat, alp, cptr, cidx, src, b1, hbf, nullptr, nullptr);

    // layer 2
    gemm_bf16<<<dim3(48, 26), 256, 0, stream>>>(hbf, Wt, feat);
    eler<<<6624, 256, 0, stream>>>(feat, al2, ar2, el, er);
    edge_softmax<<<104, 256, 0, stream>>>(el, er, cptr, cidx, src, alp);
    msg_agg<1><<<MM, 256, 0, stream>>>(feat, alp, cptr, cidx, src, b2, nullptr, h0, out);
}

// Round 2
// 292.775 us; speedup vs baseline: 1.4120x; 1.4120x over previous
//
#include <hip/hip_runtime.h>

#define BB 16
#define NNODE 207
#define TTS 12
#define NE 1863
#define NEP 1872  // NE padded to multiple of 16
#define NH 8
#define FD 768
#define HFD 6144
#define MM 3312   // BB*NNODE
#define MP 3328   // padded to 26*128

typedef short bf16x8 __attribute__((ext_vector_type(8)));
typedef float f32x4 __attribute__((ext_vector_type(4)));

typedef __attribute__((address_space(3))) unsigned int lds_u32;
typedef __attribute__((address_space(1))) const unsigned int glb_u32;

__device__ __forceinline__ unsigned short f2b(float f) {
    unsigned int u = __float_as_uint(f);
    u = (u + 0x7FFFu + ((u >> 16) & 1u)) >> 16;
    return (unsigned short)u;
}
__device__ __forceinline__ float b2f(unsigned short b) {
    return __uint_as_float(((unsigned int)b) << 16);
}

// ---------------- W transpose: W[k][n] (f32) -> Wt[n][k] (bf16) ----------------
__global__ __launch_bounds__(256) void transpose_w(const float* __restrict__ W,
                                                   unsigned short* __restrict__ Wt) {
    __shared__ float tile[64][65];
    const int k0 = blockIdx.x * 64;  // 768/64 = 12
    const int n0 = blockIdx.y * 64;  // 6144/64 = 96
    const int c = threadIdx.x & 63, r0 = threadIdx.x >> 6;
#pragma unroll
    for (int i = 0; i < 16; i++) {
        int r = r0 + i * 4;
        tile[r][c] = W[(size_t)(k0 + r) * HFD + n0 + c];
    }
    __syncthreads();
#pragma unroll
    for (int i = 0; i < 16; i++) {
        int r = r0 + i * 4;
        Wt[(size_t)(n0 + r) * FD + k0 + c] = f2b(tile[c][r]);
    }
}

// ---------------- 1x1 convs -> h0 (f32) + hbf (bf16, padded rows zeroed) -------
__global__ __launch_bounds__(256) void prep_h(const float* __restrict__ x,
                                              const float* __restrict__ Ws, const float* __restrict__ bs,
                                              const float* __restrict__ Wc, const float* __restrict__ bc,
                                              float* __restrict__ h0, unsigned short* __restrict__ hbf) {
    const int bn = blockIdx.x;
    const int t = threadIdx.x;
    if (bn >= MM) {
#pragma unroll
        for (int c = 0; c < 3; c++) hbf[(size_t)bn * FD + c * 256 + t] = 0;
        return;
    }
    const int b = bn / NNODE, n = bn % NNODE;
#pragma unroll
    for (int c = 0; c < 3; c++) {
        int idx = c * 256 + t;          // 0..767
        int e = idx / TTS, tt = idx % TTS;
        float x0 = x[((size_t)(b * 2 + 0) * NNODE + n) * TTS + tt];
        float x1 = x[((size_t)(b * 2 + 1) * NNODE + n) * TTS + tt];
        float s1 = Ws[e * 2] * x0 + Ws[e * 2 + 1] * x1 + bs[e];
        float s2 = Wc[e * 2] * x0 + Wc[e * 2 + 1] * x1 + bc[e];
        s2 = s2 > 0.f ? s2 : 0.01f * s2;
        float v = s1 + s2;
        h0[(size_t)bn * FD + idx] = v;
        hbf[(size_t)bn * FD + idx] = f2b(v);
    }
}

// ---------------- deterministic parallel CSR by dst ----------------------------
// pos(e) = #{e': dst[e'] < dst[e]} + #{e' < e: dst[e'] == dst[e]}
// ptr[n] = #{e': dst[e'] < n}
__global__ __launch_bounds__(256) void build_csr2(const int* __restrict__ dst,
                                                  int* __restrict__ ptr, int* __restrict__ cidx) {
    __shared__ int dl[NEP];
    const int t = threadIdx.x;
    for (int i = t; i < NEP; i += 256) dl[i] = (i < NE) ? dst[i] : 0x0FFFFFFF;
    __syncthreads();
    if (blockIdx.x < 8) {
        const int e = blockIdx.x * 256 + t;
        const int d = (e < NE) ? dl[e] : -1;
        int pos = 0;
#pragma unroll 16
        for (int i = 0; i < NEP; i++) {
            int di = dl[i];
            pos += (int)(di < d) + (int)((i < e) & (di == d));
        }
        if (e < NE) cidx[pos] = e;
    } else {
        if (t <= NNODE) {
            int cnt = 0;
#pragma unroll 16
            for (int i = 0; i < NEP; i++) cnt += (int)(dl[i] < t);
            ptr[t] = cnt;   // ptr[NNODE] = NE (all real dst < NNODE, pads are huge)
        }
    }
}

// ---------------- MFMA GEMM (m97 structure): C = A[MP][FD] @ Bt[HFD][FD]^T -----
// Linear LDS [128][32] bf16, staged via global_load_lds width=16.
__global__ __launch_bounds__(256) void gemm_bf16(const unsigned short* __restrict__ A,
                                                 const unsigned short* __restrict__ Bt,
                                                 unsigned short* __restrict__ C) {
    __shared__ __align__(16) unsigned short Alds[128 * 32];
    __shared__ __align__(16) unsigned short Blds[128 * 32];
    const int t = threadIdx.x;
    const int lane = t & 63;
    const int wv = t >> 6;
    const int wr = (wv >> 1) * 64, wc = (wv & 1) * 64;
    const int mt = blockIdx.y * 128, nt = blockIdx.x * 128;
    const int lm = lane & 15;
    const int kb = (lane >> 4) * 8;

    // staging geometry: wave wv stages LDS chunks (2*wv) and (2*wv+1) of each
    // matrix; one chunk = 16 rows x 32 cols bf16 = 1024B; lane i writes 16B at
    // chunk_base + i*16  ->  row_in_chunk = i/4, col_seg = (i%4)*8 elems.
    const int r0 = (wv * 2) * 16 + (lane >> 2);
    const int r1 = (wv * 2 + 1) * 16 + (lane >> 2);
    const int cseg = (lane & 3) * 8;
    const size_t aoff0 = (size_t)(mt + r0) * FD + cseg;
    const size_t aoff1 = (size_t)(mt + r1) * FD + cseg;
    const size_t boff0 = (size_t)(nt + r0) * FD + cseg;
    const size_t boff1 = (size_t)(nt + r1) * FD + cseg;
    unsigned short* la0 = Alds + (size_t)(wv * 2) * 512;
    unsigned short* la1 = Alds + (size_t)(wv * 2 + 1) * 512;
    unsigned short* lb0 = Blds + (size_t)(wv * 2) * 512;
    unsigned short* lb1 = Blds + (size_t)(wv * 2 + 1) * 512;

    f32x4 acc[4][4] = {};
    for (int ks = 0; ks < FD; ks += 32) {
        __builtin_amdgcn_global_load_lds((glb_u32*)(A + aoff0 + ks), (lds_u32*)la0, 16, 0, 0);
        __builtin_amdgcn_global_load_lds((glb_u32*)(A + aoff1 + ks), (lds_u32*)la1, 16, 0, 0);
        __builtin_amdgcn_global_load_lds((glb_u32*)(Bt + boff0 + ks), (lds_u32*)lb0, 16, 0, 0);
        __builtin_amdgcn_global_load_lds((glb_u32*)(Bt + boff1 + ks), (lds_u32*)lb1, 16, 0, 0);
        __syncthreads();   // drains vmcnt before ds_read
        bf16x8 af[4], bfv[4];
#pragma unroll
        for (int i = 0; i < 4; i++) af[i] = *(const bf16x8*)(Alds + (wr + i * 16 + lm) * 32 + kb);
#pragma unroll
        for (int j = 0; j < 4; j++) bfv[j] = *(const bf16x8*)(Blds + (wc + j * 16 + lm) * 32 + kb);
#pragma unroll
        for (int i = 0; i < 4; i++)
#pragma unroll
            for (int j = 0; j < 4; j++)
                acc[i][j] = __builtin_amdgcn_mfma_f32_16x16x32_bf16(af[i], bfv[j], acc[i][j], 0, 0, 0);
        __syncthreads();   // LDS reads done before next-iter overwrite
    }
    const int rbase = (lane >> 4) * 4;
#pragma unroll
    for (int i = 0; i < 4; i++) {
#pragma unroll
        for (int r = 0; r < 4; r++) {
            int grow = mt + wr + i * 16 + rbase + r;
            if (grow < MM) {
#pragma unroll
                for (int j = 0; j < 4; j++) {
                    int gcol = nt + wc + j * 16 + lm;
                    C[(size_t)grow * HFD + gcol] = f2b(acc[i][j][r]);
                }
            }
        }
    }
}

// ---------------- el/er: one wave per (bn, head) -------------------------------
__global__ __launch_bounds__(256) void eler(const unsigned short* __restrict__ feat,
                                            const float* __restrict__ al, const float* __restrict__ ar,
                                            float* __restrict__ el, float* __restrict__ er) {
    const int p = blockIdx.x * 4 + (threadIdx.x >> 6);  // 26496 pairs
    const int lane = threadIdx.x & 63;
    const int bn = p >> 3, hh = p & 7;
    const size_t base = (size_t)bn * HFD + hh * FD;
    float sl = 0.f, sr = 0.f;
#pragma unroll
    for (int j = 0; j < 12; j++) {
        int f = lane + j * 64;
        float fv = b2f(feat[base + f]);
        sl += fv * al[hh * FD + f];
        sr += fv * ar[hh * FD + f];
    }
#pragma unroll
    for (int off = 32; off > 0; off >>= 1) {
        sl += __shfl_down(sl, off);
        sr += __shfl_down(sr, off);
    }
    if (lane == 0) {
        el[bn * NH + hh] = sl;
        er[bn * NH + hh] = sr;
    }
}

// ---------------- edge softmax: one thread per (b,n,h) -------------------------
__global__ __launch_bounds__(256) void edge_softmax(const float* __restrict__ el, const float* __restrict__ er,
                                                    const int* __restrict__ cptr, const int* __restrict__ cidx,
                                                    const int* __restrict__ src, float* __restrict__ alp) {
    const int t = blockIdx.x * 256 + threadIdx.x;
    if (t >= BB * NNODE * NH) return;
    const int hh = t & 7;
    const int n = (t >> 3) % NNODE;
    const int b = t / (NNODE * NH);
    const float erv = er[(b * NNODE + n) * NH + hh];
    const int p0 = cptr[n], p1 = cptr[n + 1];
    float m = -1e30f;
    for (int j = p0; j < p1; j++) {
        int e = cidx[j];
        float s = el[(b * NNODE + src[e]) * NH + hh] + erv;
        s = s > 0.f ? s : 0.2f * s;
        m = fmaxf(m, s);
    }
    float den = 0.f;
    for (int j = p0; j < p1; j++) {
        int e = cidx[j];
        float s = el[(b * NNODE + src[e]) * NH + hh] + erv;
        s = s > 0.f ? s : 0.2f * s;
        float ex = expf(s - m);
        den += ex;
        alp[((size_t)b * NE + e) * NH + hh] = ex;
    }
    const float inv = 1.f / den;
    for (int j = p0; j < p1; j++) {
        int e = cidx[j];
        alp[((size_t)b * NE + e) * NH + hh] *= inv;
    }
}

// ---------------- message passing + elu + head-mean ----------------------------
template <int LAST>
__global__ __launch_bounds__(256) void msg_agg(const unsigned short* __restrict__ feat,
                                               const float* __restrict__ alp,
                                               const int* __restrict__ cptr, const int* __restrict__ cidx,
                                               const int* __restrict__ src, const float* __restrict__ bias,
                                               unsigned short* __restrict__ hbf_out,
                                               const float* __restrict__ h0, float* __restrict__ out) {
    __shared__ float rstl[HFD];         // 24 KB
    __shared__ int src_l[32];
    __shared__ float alph[32][NH];
    // XCD-aware bijective swizzle: nwg = 3312 = 8*414, consecutive bn share batch b
    const int bn = (blockIdx.x & 7) * (MM / 8) + (blockIdx.x >> 3);
    const int b = bn / NNODE, n = bn % NNODE;
    const int t = threadIdx.x;
    const int h0i = t / 96, h1i = (256 + t) / 96, h2i = (512 + t) / 96;
    float acc[3][8] = {};
    const int p0 = cptr[n], p1 = cptr[n + 1];
    for (int base = p0; base < p1; base += 32) {
        const int cnt = min(32, p1 - base);
        if (t < cnt) src_l[t] = src[cidx[base + t]];
        {
            int j = t >> 3, hh = t & 7;
            if (j < cnt) alph[j][hh] = alp[((size_t)b * NE + cidx[base + j]) * NH + hh];
        }
        __syncthreads();
        for (int j2 = 0; j2 < cnt; j2++) {
            const size_t srow = (size_t)(b * NNODE + src_l[j2]) * HFD;
            const float a0 = alph[j2][h0i], a1 = alph[j2][h1i], a2 = alph[j2][h2i];
            uint4 pk;
            unsigned int w;
            pk = *(const uint4*)(feat + srow + (size_t)(0 * 256 + t) * 8);
            w = pk.x; acc[0][0] += a0 * b2f((unsigned short)w); acc[0][1] += a0 * b2f((unsigned short)(w >> 16));
            w = pk.y; acc[0][2] += a0 * b2f((unsigned short)w); acc[0][3] += a0 * b2f((unsigned short)(w >> 16));
            w = pk.z; acc[0][4] += a0 * b2f((unsigned short)w); acc[0][5] += a0 * b2f((unsigned short)(w >> 16));
            w = pk.w; acc[0][6] += a0 * b2f((unsigned short)w); acc[0][7] += a0 * b2f((unsigned short)(w >> 16));
            pk = *(const uint4*)(feat + srow + (size_t)(1 * 256 + t) * 8);
            w = pk.x; acc[1][0] += a1 * b2f((unsigned short)w); acc[1][1] += a1 * b2f((unsigned short)(w >> 16));
            w = pk.y; acc[1][2] += a1 * b2f((unsigned short)w); acc[1][3] += a1 * b2f((unsigned short)(w >> 16));
            w = pk.z; acc[1][4] += a1 * b2f((unsigned short)w); acc[1][5] += a1 * b2f((unsigned short)(w >> 16));
            w = pk.w; acc[1][6] += a1 * b2f((unsigned short)w); acc[1][7] += a1 * b2f((unsigned short)(w >> 16));
            pk = *(const uint4*)(feat + srow + (size_t)(2 * 256 + t) * 8);
            w = pk.x; acc[2][0] += a2 * b2f((unsigned short)w); acc[2][1] += a2 * b2f((unsigned short)(w >> 16));
            w = pk.y; acc[2][2] += a2 * b2f((unsigned short)w); acc[2][3] += a2 * b2f((unsigned short)(w >> 16));
            w = pk.z; acc[2][4] += a2 * b2f((unsigned short)w); acc[2][5] += a2 * b2f((unsigned short)(w >> 16));
            w = pk.w; acc[2][6] += a2 * b2f((unsigned short)w); acc[2][7] += a2 * b2f((unsigned short)(w >> 16));
        }
        __syncthreads();
    }
#pragma unroll
    for (int c = 0; c < 3; c++) {
        int v = c * 256 + t;
#pragma unroll
        for (int u = 0; u < 8; u++) rstl[v * 8 + u] = acc[c][u];
    }
    __syncthreads();
#pragma unroll
    for (int q = 0; q < 3; q++) {
        int f = q * 256 + t;
        float val = 0.f;
#pragma unroll
        for (int hh = 0; hh < 8; hh++) {
            float r = rstl[hh * FD + f] + bias[hh * FD + f];
            val += (r > 0.f) ? r : (expf(r) - 1.f);
        }
        val *= 0.125f;
        if (LAST) {
            int e_ = f / TTS, tt_ = f % TTS;
            out[((size_t)(b * 64 + e_) * NNODE + n) * TTS + tt_] = h0[(size_t)bn * FD + f] + val;
        } else {
            hbf_out[(size_t)bn * FD + f] = f2b(val);
        }
    }
}

extern "C" void kernel_launch(void* const* d_in, const int* in_sizes, int n_in,
                              void* d_out, int out_size, void* d_ws, size_t ws_size,
                              hipStream_t stream) {
    const float* x = (const float*)d_in[0];
    const int* src = (const int*)d_in[1];
    const int* dst = (const int*)d_in[2];
    const float* Ws = (const float*)d_in[3];
    const float* bs = (const float*)d_in[4];
    const float* Wc = (const float*)d_in[5];
    const float* bc = (const float*)d_in[6];
    const float* W1 = (const float*)d_in[7];
    const float* al1 = (const float*)d_in[8];
    const float* ar1 = (const float*)d_in[9];
    const float* b1 = (const float*)d_in[10];
    const float* W2 = (const float*)d_in[11];
    const float* al2 = (const float*)d_in[12];
    const float* ar2 = (const float*)d_in[13];
    const float* b2 = (const float*)d_in[14];
    float* out = (float*)d_out;

    char* w = (char*)d_ws;
    size_t off = 0;
    auto alloc = [&](size_t bytes) -> void* {
        void* p = w + off;
        off = (off + bytes + 255) & ~(size_t)255;
        return p;
    };
    float* h0 = (float*)alloc((size_t)MM * FD * 4);
    unsigned short* hbf = (unsigned short*)alloc((size_t)MP * FD * 2);
    unsigned short* Wt = (unsigned short*)alloc((size_t)HFD * FD * 2);
    unsigned short* feat = (unsigned short*)alloc((size_t)MM * HFD * 2);
    float* el = (float*)alloc((size_t)MM * NH * 4);
    float* er = (float*)alloc((size_t)MM * NH * 4);
    float* alp = (float*)alloc((size_t)BB * NE * NH * 4);
    int* cptr = (int*)alloc((NNODE + 1) * 4);
    int* cidx = (int*)alloc(NE * 4);

    // prep
    transpose_w<<<dim3(12, 96), 256, 0, stream>>>(W1, Wt);
    prep_h<<<MP, 256, 0, stream>>>(x, Ws, bs, Wc, bc, h0, hbf);
    build_csr2<<<9, 256, 0, stream>>>(dst, cptr, cidx);

    // layer 1
    gemm_bf16<<<dim3(48, 26), 256, 0, stream>>>(hbf, Wt, feat);
    transpose_w<<<dim3(12, 96), 256, 0, stream>>>(W2, Wt);  // Wt free after gemm1
    eler<<<6624, 256, 0, stream>>>(feat, al1, ar1, el, er);
    edge_softmax<<<104, 256, 0, stream>>>(el, er, cptr, cidx, src, alp);
    msg_agg<0><<<MM, 256, 0, stream>>>(feat, alp, cptr, cidx, src, b1, hbf, nullptr, nullptr);

    // layer 2
    gemm_bf16<<<dim3(48, 26), 256, 0, stream>>>(hbf, Wt, feat);
    eler<<<6624, 256, 0, stream>>>(feat, al2, ar2, el, er);
    edge_softmax<<<104, 256, 0, stream>>>(el, er, cptr, cidx, src, alp);
    msg_agg<1><<<MM, 256, 0, stream>>>(feat, alp, cptr, cidx, src, b2, nullptr, h0, out);
}

// Round 3
// 238.888 us; speedup vs baseline: 1.7305x; 1.2256x over previous
//
#include <hip/hip_runtime.h>

#define BB 16
#define NNODE 207
#define TTS 12
#define NE 1863
#define NEP2 1920 // NE padded to 30*64
#define NH 8
#define FD 768
#define HFD 6144
#define MM 3312   // BB*NNODE
#define MP 3328   // padded to 26*128

typedef short bf16x8 __attribute__((ext_vector_type(8)));
typedef float f32x4 __attribute__((ext_vector_type(4)));

typedef __attribute__((address_space(3))) unsigned int lds_u32;
typedef __attribute__((address_space(1))) const unsigned int glb_u32;

__device__ __forceinline__ unsigned short f2b(float f) {
    unsigned int u = __float_as_uint(f);
    u = (u + 0x7FFFu + ((u >> 16) & 1u)) >> 16;
    return (unsigned short)u;
}
__device__ __forceinline__ float b2f(unsigned short b) {
    return __uint_as_float(((unsigned int)b) << 16);
}

// ---------------- W transpose: W[k][n] (f32) -> Wt[n][k] (bf16) ----------------
__global__ __launch_bounds__(256) void transpose_w(const float* __restrict__ W,
                                                   unsigned short* __restrict__ Wt) {
    __shared__ float tile[64][65];
    const int k0 = blockIdx.x * 64;  // 768/64 = 12
    const int n0 = blockIdx.y * 64;  // 6144/64 = 96
    const int c = threadIdx.x & 63, r0 = threadIdx.x >> 6;
#pragma unroll
    for (int i = 0; i < 16; i++) {
        int r = r0 + i * 4;
        tile[r][c] = W[(size_t)(k0 + r) * HFD + n0 + c];
    }
    __syncthreads();
#pragma unroll
    for (int i = 0; i < 16; i++) {
        int r = r0 + i * 4;
        Wt[(size_t)(n0 + r) * FD + k0 + c] = f2b(tile[c][r]);
    }
}

// ---------------- 1x1 convs -> h0 (f32) + hbf (bf16, padded rows zeroed) -------
__global__ __launch_bounds__(256) void prep_h(const float* __restrict__ x,
                                              const float* __restrict__ Ws, const float* __restrict__ bs,
                                              const float* __restrict__ Wc, const float* __restrict__ bc,
                                              float* __restrict__ h0, unsigned short* __restrict__ hbf) {
    const int bn = blockIdx.x;
    const int t = threadIdx.x;
    if (bn >= MM) {
#pragma unroll
        for (int c = 0; c < 3; c++) hbf[(size_t)bn * FD + c * 256 + t] = 0;
        return;
    }
    const int b = bn / NNODE, n = bn % NNODE;
#pragma unroll
    for (int c = 0; c < 3; c++) {
        int idx = c * 256 + t;          // 0..767
        int e = idx / TTS, tt = idx % TTS;
        float x0 = x[((size_t)(b * 2 + 0) * NNODE + n) * TTS + tt];
        float x1 = x[((size_t)(b * 2 + 1) * NNODE + n) * TTS + tt];
        float s1 = Ws[e * 2] * x0 + Ws[e * 2 + 1] * x1 + bs[e];
        float s2 = Wc[e * 2] * x0 + Wc[e * 2 + 1] * x1 + bc[e];
        s2 = s2 > 0.f ? s2 : 0.01f * s2;
        float v = s1 + s2;
        h0[(size_t)bn * FD + idx] = v;
        hbf[(size_t)bn * FD + idx] = f2b(v);
    }
}

// ---------------- deterministic parallel CSR, wave-per-edge / wave-per-node ----
// pos(e) = #{e': dst[e'] < dst[e]} + #{e' < e: dst[e'] == dst[e]}
// ptr[n] = #{e': dst[e'] < n}
#define CSR_EBLK 468  // 468 blocks x 4 waves = 1872 edge-waves
__global__ __launch_bounds__(256) void build_csr3(const int* __restrict__ dst,
                                                  int* __restrict__ ptr, int* __restrict__ cidx) {
    __shared__ int dl[NEP2];
    const int t = threadIdx.x;
    const int wv = t >> 6, lane = t & 63;
    for (int i = t; i < NEP2; i += 256) dl[i] = (i < NE) ? dst[i] : 0x0FFFFFFF;
    __syncthreads();
    if (blockIdx.x < CSR_EBLK) {
        const int e = blockIdx.x * 4 + wv;
        if (e >= NE) return;
        const int d = dl[e];
        int pos = 0;
#pragma unroll
        for (int j = 0; j < 30; j++) {
            int i = lane + j * 64;
            int di = dl[i];
            pos += (int)(di < d) + (int)((i < e) & (di == d));
        }
#pragma unroll
        for (int off = 32; off > 0; off >>= 1) pos += __shfl_down(pos, off);
        if (lane == 0) cidx[pos] = e;
    } else {
        const int n = (blockIdx.x - CSR_EBLK) * 4 + wv;  // 0..207
        if (n > NNODE) return;
        int cnt = 0;
#pragma unroll
        for (int j = 0; j < 30; j++) cnt += (int)(dl[lane + j * 64] < n);
#pragma unroll
        for (int off = 32; off > 0; off >>= 1) cnt += __shfl_down(cnt, off);
        if (lane == 0) ptr[n] = cnt;  // ptr[NNODE] = NE
    }
}

// ---------------- MFMA GEMM (m97 structure): C = A[MP][FD] @ Bt[HFD][FD]^T -----
// Linear LDS [128][32] bf16, staged via global_load_lds width=16.
__global__ __launch_bounds__(256) void gemm_bf16(const unsigned short* __restrict__ A,
                                                 const unsigned short* __restrict__ Bt,
                                                 unsigned short* __restrict__ C) {
    __shared__ __align__(16) unsigned short Alds[128 * 32];
    __shared__ __align__(16) unsigned short Blds[128 * 32];
    const int t = threadIdx.x;
    const int lane = t & 63;
    const int wv = t >> 6;
    const int wr = (wv >> 1) * 64, wc = (wv & 1) * 64;
    const int mt = blockIdx.y * 128, nt = blockIdx.x * 128;
    const int lm = lane & 15;
    const int kb = (lane >> 4) * 8;

    const int r0 = (wv * 2) * 16 + (lane >> 2);
    const int r1 = (wv * 2 + 1) * 16 + (lane >> 2);
    const int cseg = (lane & 3) * 8;
    const size_t aoff0 = (size_t)(mt + r0) * FD + cseg;
    const size_t aoff1 = (size_t)(mt + r1) * FD + cseg;
    const size_t boff0 = (size_t)(nt + r0) * FD + cseg;
    const size_t boff1 = (size_t)(nt + r1) * FD + cseg;
    unsigned short* la0 = Alds + (size_t)(wv * 2) * 512;
    unsigned short* la1 = Alds + (size_t)(wv * 2 + 1) * 512;
    unsigned short* lb0 = Blds + (size_t)(wv * 2) * 512;
    unsigned short* lb1 = Blds + (size_t)(wv * 2 + 1) * 512;

    f32x4 acc[4][4] = {};
    for (int ks = 0; ks < FD; ks += 32) {
        __builtin_amdgcn_global_load_lds((glb_u32*)(A + aoff0 + ks), (lds_u32*)la0, 16, 0, 0);
        __builtin_amdgcn_global_load_lds((glb_u32*)(A + aoff1 + ks), (lds_u32*)la1, 16, 0, 0);
        __builtin_amdgcn_global_load_lds((glb_u32*)(Bt + boff0 + ks), (lds_u32*)lb0, 16, 0, 0);
        __builtin_amdgcn_global_load_lds((glb_u32*)(Bt + boff1 + ks), (lds_u32*)lb1, 16, 0, 0);
        __syncthreads();
        bf16x8 af[4], bfv[4];
#pragma unroll
        for (int i = 0; i < 4; i++) af[i] = *(const bf16x8*)(Alds + (wr + i * 16 + lm) * 32 + kb);
#pragma unroll
        for (int j = 0; j < 4; j++) bfv[j] = *(const bf16x8*)(Blds + (wc + j * 16 + lm) * 32 + kb);
#pragma unroll
        for (int i = 0; i < 4; i++)
#pragma unroll
            for (int j = 0; j < 4; j++)
                acc[i][j] = __builtin_amdgcn_mfma_f32_16x16x32_bf16(af[i], bfv[j], acc[i][j], 0, 0, 0);
        __syncthreads();
    }
    const int rbase = (lane >> 4) * 4;
#pragma unroll
    for (int i = 0; i < 4; i++) {
#pragma unroll
        for (int r = 0; r < 4; r++) {
            int grow = mt + wr + i * 16 + rbase + r;
            if (grow < MM) {
#pragma unroll
                for (int j = 0; j < 4; j++) {
                    int gcol = nt + wc + j * 16 + lm;
                    C[(size_t)grow * HFD + gcol] = f2b(acc[i][j][r]);
                }
            }
        }
    }
}

// ---------------- el/er: one wave per (bn, head) -------------------------------
__global__ __launch_bounds__(256) void eler(const unsigned short* __restrict__ feat,
                                            const float* __restrict__ al, const float* __restrict__ ar,
                                            float* __restrict__ el, float* __restrict__ er) {
    const int p = blockIdx.x * 4 + (threadIdx.x >> 6);  // 26496 pairs
    const int lane = threadIdx.x & 63;
    const int bn = p >> 3, hh = p & 7;
    const size_t base = (size_t)bn * HFD + hh * FD;
    float sl = 0.f, sr = 0.f;
#pragma unroll
    for (int j = 0; j < 12; j++) {
        int f = lane + j * 64;
        float fv = b2f(feat[base + f]);
        sl += fv * al[hh * FD + f];
        sr += fv * ar[hh * FD + f];
    }
#pragma unroll
    for (int off = 32; off > 0; off >>= 1) {
        sl += __shfl_down(sl, off);
        sr += __shfl_down(sr, off);
    }
    if (lane == 0) {
        el[bn * NH + hh] = sl;
        er[bn * NH + hh] = sr;
    }
}

// ---------------- edge softmax: one thread per (b,n,h) -------------------------
__global__ __launch_bounds__(256) void edge_softmax(const float* __restrict__ el, const float* __restrict__ er,
                                                    const int* __restrict__ cptr, const int* __restrict__ cidx,
                                                    const int* __restrict__ src, float* __restrict__ alp) {
    const int t = blockIdx.x * 256 + threadIdx.x;
    if (t >= BB * NNODE * NH) return;
    const int hh = t & 7;
    const int n = (t >> 3) % NNODE;
    const int b = t / (NNODE * NH);
    const float erv = er[(b * NNODE + n) * NH + hh];
    const int p0 = cptr[n], p1 = cptr[n + 1];
    float m = -1e30f;
    for (int j = p0; j < p1; j++) {
        int e = cidx[j];
        float s = el[(b * NNODE + src[e]) * NH + hh] + erv;
        s = s > 0.f ? s : 0.2f * s;
        m = fmaxf(m, s);
    }
    float den = 0.f;
    for (int j = p0; j < p1; j++) {
        int e = cidx[j];
        float s = el[(b * NNODE + src[e]) * NH + hh] + erv;
        s = s > 0.f ? s : 0.2f * s;
        float ex = expf(s - m);
        den += ex;
        alp[((size_t)b * NE + e) * NH + hh] = ex;
    }
    const float inv = 1.f / den;
    for (int j = p0; j < p1; j++) {
        int e = cidx[j];
        alp[((size_t)b * NE + e) * NH + hh] *= inv;
    }
}

// ---------------- message passing + elu + head-mean ----------------------------
template <int LAST>
__global__ __launch_bounds__(256) void msg_agg(const unsigned short* __restrict__ feat,
                                               const float* __restrict__ alp,
                                               const int* __restrict__ cptr, const int* __restrict__ cidx,
                                               const int* __restrict__ src, const float* __restrict__ bias,
                                               unsigned short* __restrict__ hbf_out,
                                               const float* __restrict__ h0, float* __restrict__ out) {
    __shared__ float rstl[HFD];         // 24 KB
    __shared__ int src_l[32];
    __shared__ float alph[32][NH];
    // XCD-aware bijective swizzle: nwg = 3312 = 8*414, consecutive bn share batch b
    const int bn = (blockIdx.x & 7) * (MM / 8) + (blockIdx.x >> 3);
    const int b = bn / NNODE, n = bn % NNODE;
    const int t = threadIdx.x;
    const int h0i = t / 96, h1i = (256 + t) / 96, h2i = (512 + t) / 96;
    float acc[3][8] = {};
    const int p0 = cptr[n], p1 = cptr[n + 1];
    for (int base = p0; base < p1; base += 32) {
        const int cnt = min(32, p1 - base);
        if (t < cnt) src_l[t] = src[cidx[base + t]];
        {
            int j = t >> 3, hh = t & 7;
            if (j < cnt) alph[j][hh] = alp[((size_t)b * NE + cidx[base + j]) * NH + hh];
        }
        __syncthreads();
        for (int j2 = 0; j2 < cnt; j2++) {
            const size_t srow = (size_t)(b * NNODE + src_l[j2]) * HFD;
            const float a0 = alph[j2][h0i], a1 = alph[j2][h1i], a2 = alph[j2][h2i];
            uint4 pk;
            unsigned int w;
            pk = *(const uint4*)(feat + srow + (size_t)(0 * 256 + t) * 8);
            w = pk.x; acc[0][0] += a0 * b2f((unsigned short)w); acc[0][1] += a0 * b2f((unsigned short)(w >> 16));
            w = pk.y; acc[0][2] += a0 * b2f((unsigned short)w); acc[0][3] += a0 * b2f((unsigned short)(w >> 16));
            w = pk.z; acc[0][4] += a0 * b2f((unsigned short)w); acc[0][5] += a0 * b2f((unsigned short)(w >> 16));
            w = pk.w; acc[0][6] += a0 * b2f((unsigned short)w); acc[0][7] += a0 * b2f((unsigned short)(w >> 16));
            pk = *(const uint4*)(feat + srow + (size_t)(1 * 256 + t) * 8);
            w = pk.x; acc[1][0] += a1 * b2f((unsigned short)w); acc[1][1] += a1 * b2f((unsigned short)(w >> 16));
            w = pk.y; acc[1][2] += a1 * b2f((unsigned short)w); acc[1][3] += a1 * b2f((unsigned short)(w >> 16));
            w = pk.z; acc[1][4] += a1 * b2f((unsigned short)w); acc[1][5] += a1 * b2f((unsigned short)(w >> 16));
            w = pk.w; acc[1][6] += a1 * b2f((unsigned short)w); acc[1][7] += a1 * b2f((unsigned short)(w >> 16));
            pk = *(const uint4*)(feat + srow + (size_t)(2 * 256 + t) * 8);
            w = pk.x; acc[2][0] += a2 * b2f((unsigned short)w); acc[2][1] += a2 * b2f((unsigned short)(w >> 16));
            w = pk.y; acc[2][2] += a2 * b2f((unsigned short)w); acc[2][3] += a2 * b2f((unsigned short)(w >> 16));
            w = pk.z; acc[2][4] += a2 * b2f((unsigned short)w); acc[2][5] += a2 * b2f((unsigned short)(w >> 16));
            w = pk.w; acc[2][6] += a2 * b2f((unsigned short)w); acc[2][7] += a2 * b2f((unsigned short)(w >> 16));
        }
        __syncthreads();
    }
#pragma unroll
    for (int c = 0; c < 3; c++) {
        int v = c * 256 + t;
#pragma unroll
        for (int u = 0; u < 8; u++) rstl[v * 8 + u] = acc[c][u];
    }
    __syncthreads();
#pragma unroll
    for (int q = 0; q < 3; q++) {
        int f = q * 256 + t;
        float val = 0.f;
#pragma unroll
        for (int hh = 0; hh < 8; hh++) {
            float r = rstl[hh * FD + f] + bias[hh * FD + f];
            val += (r > 0.f) ? r : (expf(r) - 1.f);
        }
        val *= 0.125f;
        if (LAST) {
            int e_ = f / TTS, tt_ = f % TTS;
            out[((size_t)(b * 64 + e_) * NNODE + n) * TTS + tt_] = h0[(size_t)bn * FD + f] + val;
        } else {
            hbf_out[(size_t)bn * FD + f] = f2b(val);
        }
    }
}

extern "C" void kernel_launch(void* const* d_in, const int* in_sizes, int n_in,
                              void* d_out, int out_size, void* d_ws, size_t ws_size,
                              hipStream_t stream) {
    const float* x = (const float*)d_in[0];
    const int* src = (const int*)d_in[1];
    const int* dst = (const int*)d_in[2];
    const float* Ws = (const float*)d_in[3];
    const float* bs = (const float*)d_in[4];
    const float* Wc = (const float*)d_in[5];
    const float* bc = (const float*)d_in[6];
    const float* W1 = (const float*)d_in[7];
    const float* al1 = (const float*)d_in[8];
    const float* ar1 = (const float*)d_in[9];
    const float* b1 = (const float*)d_in[10];
    const float* W2 = (const float*)d_in[11];
    const float* al2 = (const float*)d_in[12];
    const float* ar2 = (const float*)d_in[13];
    const float* b2 = (const float*)d_in[14];
    float* out = (float*)d_out;

    char* w = (char*)d_ws;
    size_t off = 0;
    auto alloc = [&](size_t bytes) -> void* {
        void* p = w + off;
        off = (off + bytes + 255) & ~(size_t)255;
        return p;
    };
    float* h0 = (float*)alloc((size_t)MM * FD * 4);
    unsigned short* hbf = (unsigned short*)alloc((size_t)MP * FD * 2);
    unsigned short* Wt = (unsigned short*)alloc((size_t)HFD * FD * 2);
    unsigned short* feat = (unsigned short*)alloc((size_t)MM * HFD * 2);
    float* el = (float*)alloc((size_t)MM * NH * 4);
    float* er = (float*)alloc((size_t)MM * NH * 4);
    float* alp = (float*)alloc((size_t)BB * NE * NH * 4);
    int* cptr = (int*)alloc((NNODE + 1) * 4);
    int* cidx = (int*)alloc(NE * 4);

    // prep
    transpose_w<<<dim3(12, 96), 256, 0, stream>>>(W1, Wt);
    prep_h<<<MP, 256, 0, stream>>>(x, Ws, bs, Wc, bc, h0, hbf);
    build_csr3<<<CSR_EBLK + 52, 256, 0, stream>>>(dst, cptr, cidx);

    // layer 1
    gemm_bf16<<<dim3(48, 26), 256, 0, stream>>>(hbf, Wt, feat);
    transpose_w<<<dim3(12, 96), 256, 0, stream>>>(W2, Wt);  // Wt free after gemm1
    eler<<<6624, 256, 0, stream>>>(feat, al1, ar1, el, er);
    edge_softmax<<<104, 256, 0, stream>>>(el, er, cptr, cidx, src, alp);
    msg_agg<0><<<MM, 256, 0, stream>>>(feat, alp, cptr, cidx, src, b1, hbf, nullptr, nullptr);

    // layer 2
    gemm_bf16<<<dim3(48, 26), 256, 0, stream>>>(hbf, Wt, feat);
    eler<<<6624, 256, 0, stream>>>(feat, al2, ar2, el, er);
    edge_softmax<<<104, 256, 0, stream>>>(el, er, cptr, cidx, src, alp);
    msg_agg<1><<<MM, 256, 0, stream>>>(feat, alp, cptr, cidx, src, b2, nullptr, h0, out);
}